// Round 10
// baseline (148.053 us; speedup 1.0000x reference)
//
#include <hip/hip_runtime.h>
#include <hip/hip_bf16.h>
#include <stdint.h>

#define N_NODES   16384
#define DIMM      256
#define HEADS     8
#define HDIM      32
#define NUM_GLOBAL 4
#define N_TOT     (N_NODES + NUM_GLOBAL)   // 16388
#define E_LOCAL   131072
#define E_EXP     65536
#define E_CSR     (E_LOCAL + E_EXP)        // 196608
#define ADJ_CAP   64                       // P(Poisson(12) >= 64) ~ 1e-26

typedef __hip_bfloat16 bf16;
typedef __attribute__((ext_vector_type(8))) short short8;
typedef __attribute__((ext_vector_type(8))) unsigned short ush8;
typedef __attribute__((ext_vector_type(4))) short sh4;
typedef __attribute__((ext_vector_type(4))) float f32x4;

// guarded packed bf16 dot2 (CDNA3/4 V_DOT2_F32_BF16); scalar fallback kept
#if defined(__has_builtin)
#  if __has_builtin(__builtin_amdgcn_fdot2_f32_bf16)
#    define HAVE_FDOT2 1
#  endif
#endif
#ifndef HAVE_FDOT2
#  define HAVE_FDOT2 0
#endif
#if HAVE_FDOT2
typedef __attribute__((ext_vector_type(2))) __bf16 bf16x2;
#endif

__device__ __forceinline__ short f2s(float f) {
    bf16 h = __float2bfloat16(f);
    return __builtin_bit_cast(short, h);
}
__device__ __forceinline__ float bu2f(unsigned short u) {
    return __bfloat162float(__builtin_bit_cast(bf16, u));
}

// XOR swizzle: 16B chunk c of row r stored at chunk (c ^ (r&7) ^ ((r>>3)&7)).
__device__ __forceinline__ int swz(int c, int r) {
    return c ^ (r & 7) ^ ((r >> 3) & 7);
}

// ---------------------------------------------------------------------------
// prep (R22): (a) transpose Wqkv -> Wt1 bf16; (b) transpose Wout -> Wt2 bf16
//       (c) zero cnt. X-convert DELETED -- qkv stages A straight from fp32
//       (in-register cvt hides under MFMA; slab re-reads are L2 hits via the
//       XCD swizzle). Grid: 64 transpose + 16 zero = 80 blocks.
// ---------------------------------------------------------------------------
__global__ __launch_bounds__(256) void prep_kernel(
    const float* __restrict__ Wqkv, const float* __restrict__ Wout,
    bf16* __restrict__ Wt1, bf16* __restrict__ Wt2, int* __restrict__ cnt)
{
    const int b = blockIdx.x;
    const int t = threadIdx.x;
    if (b < 64) {
        __shared__ float T[64][65];
        const float* src; bf16* dst; int n0, k0, ldn;
        if (b < 48) { src = Wqkv; dst = Wt1; n0 = (b % 12) * 64; k0 = (b / 12) * 64; ldn = 768; }
        else        { int bb = b - 48; src = Wout; dst = Wt2; n0 = (bb & 3) * 64; k0 = (bb >> 2) * 64; ldn = 256; }
        #pragma unroll
        for (int i = 0; i < 4; ++i) {
            int idx = t + 256 * i;
            int r = idx >> 4, c4 = (idx & 15) * 4;
            float4 v = *(const float4*)(src + (size_t)(k0 + r) * ldn + n0 + c4);
            T[r][c4] = v.x; T[r][c4 + 1] = v.y; T[r][c4 + 2] = v.z; T[r][c4 + 3] = v.w;
        }
        __syncthreads();
        #pragma unroll
        for (int i = 0; i < 4; ++i) {
            int idx = t + 256 * i;
            int nr = idx >> 4, kk = (idx & 15) * 4;
            sh4 o;
            o[0] = f2s(T[kk][nr]);     o[1] = f2s(T[kk + 1][nr]);
            o[2] = f2s(T[kk + 2][nr]); o[3] = f2s(T[kk + 3][nr]);
            *(sh4*)(dst + (size_t)(n0 + nr) * 256 + k0 + kk) = o;
        }
    } else {
        // blocks 64..79: zero cnt (16*256 int4 = 16384 ints)
        ((int4*)cnt)[(b - 64) * 256 + t] = make_int4(0, 0, 0, 0);
    }
}

// ---------------------------------------------------------------------------
// QKV projection + fused edge-build. Blocks 0..767: padded-adjacency build.
// Blocks 768+: X_full(16388x256 fp32) @ Wqkv + b -> Qb + pair-split KVp.
// R22: A staged directly from fp32 x/gtok with in-register bf16 convert
// (Xb intermediate deleted). Single-buffered LDS (34.8 KB union) + T14
// reg-prefetch (R21). K/V stored HEAD-PAIR split
// [pair][node][Ka 64|Kb 64|Va 64|Vb 64] (R19).
// ---------------------------------------------------------------------------
__global__ __launch_bounds__(256) void qkv_mfma(
    const float* __restrict__ x, const float* __restrict__ gtok,
    const bf16* __restrict__ Wt, const float* __restrict__ bias,
    const int* __restrict__ ei, const int* __restrict__ xei,
    int* __restrict__ cnt, unsigned short* __restrict__ adjP,
    bf16* __restrict__ Qb, bf16* __restrict__ KVp)
{
    const int braw = blockIdx.x;
    const int t  = threadIdx.x;
    if (braw < 768) {
        int e = braw * 256 + t;
        int s, d;
        if (e < E_LOCAL) { s = ei[e];            d = ei[E_LOCAL + e]; }
        else             { int ee = e - E_LOCAL; s = xei[ee]; d = xei[E_EXP + ee]; }
        int pos = atomicAdd(&cnt[d], 1);
        if (pos < ADJ_CAP) adjP[(d << 6) + pos] = (unsigned short)s;
        return;
    }
    const int b = braw - 768;
    const int xcd = b & 7;
    const int i = b >> 3;                      // 0..101
    const int mt = xcd + 8 * (i / 6);          // m-tile 0..135
    if (mt >= 129) return;
    const int m0 = mt * 128;
    const int n0 = (i % 6) * 128;              // 0..640

    __shared__ __align__(16) short SM[128 * 136];  // 34.8 KB union
    short* As = SM;                  // [128][64] staging (8192 shorts)
    short* Bs = SM + 8192;           // [128][64] staging
    const int wid = t >> 6, lane = t & 63;
    const int wr = wid >> 1, wc = wid & 1;
    const int lm = lane & 15, lq = lane >> 4;

    f32x4 acc[4][4] = {};
    short8 aregs[4], bregs[4];

    int sr[4], skc[4];
    #pragma unroll
    for (int ii = 0; ii < 4; ++ii) {
        int c8 = t + 256 * ii;
        sr[ii] = c8 >> 3; skc[ii] = c8 & 7;
    }

    // fp32 -> bf16x8 staging load for A (row-guarded)
    auto loadA = [&](int ii, int kn) -> short8 {
        int row = m0 + sr[ii];
        float4 v0 = make_float4(0.f, 0.f, 0.f, 0.f), v1 = v0;
        if (row < N_NODES) {
            const float* p = x + (size_t)row * DIMM + kn + skc[ii] * 8;
            v0 = *(const float4*)p; v1 = *(const float4*)(p + 4);
        } else if (row < N_TOT) {
            const float* p = gtok + (size_t)(row - N_NODES) * DIMM + kn + skc[ii] * 8;
            v0 = *(const float4*)p; v1 = *(const float4*)(p + 4);
        }
        short8 o;
        o[0] = f2s(v0.x); o[1] = f2s(v0.y); o[2] = f2s(v0.z); o[3] = f2s(v0.w);
        o[4] = f2s(v1.x); o[5] = f2s(v1.y); o[6] = f2s(v1.z); o[7] = f2s(v1.w);
        return o;
    };

    // prologue: stage step 0
    #pragma unroll
    for (int ii = 0; ii < 4; ++ii) {
        aregs[ii] = loadA(ii, 0);
        bregs[ii] = *(const short8*)((const short*)Wt + (size_t)(n0 + sr[ii]) * 256 + skc[ii] * 8);
    }
    #pragma unroll
    for (int ii = 0; ii < 4; ++ii) {
        *(short8*)(As + sr[ii] * 64 + swz(skc[ii], sr[ii]) * 8) = aregs[ii];
        *(short8*)(Bs + sr[ii] * 64 + swz(skc[ii], sr[ii]) * 8) = bregs[ii];
    }
    __syncthreads();

    #pragma unroll
    for (int tstep = 0; tstep < 4; ++tstep) {
        // T14: issue next step's loads before compute
        if (tstep < 3) {
            const int kn = (tstep + 1) * 64;
            #pragma unroll
            for (int ii = 0; ii < 4; ++ii) {
                aregs[ii] = loadA(ii, kn);
                bregs[ii] = *(const short8*)((const short*)Wt + (size_t)(n0 + sr[ii]) * 256 + kn + skc[ii] * 8);
            }
        }
        // compute on current buffer
        #pragma unroll
        for (int kk = 0; kk < 2; ++kk) {
            const int c = kk * 4 + lq;
            short8 af[4], bfq[4];
            #pragma unroll
            for (int mi = 0; mi < 4; ++mi) {
                int r = wr * 64 + mi * 16 + lm;
                af[mi] = *(const short8*)(As + r * 64 + swz(c, r) * 8);
            }
            #pragma unroll
            for (int ni = 0; ni < 4; ++ni) {
                int n = wc * 64 + ni * 16 + lm;
                bfq[ni] = *(const short8*)(Bs + n * 64 + swz(c, n) * 8);
            }
            #pragma unroll
            for (int mi = 0; mi < 4; ++mi)
                #pragma unroll
                for (int ni = 0; ni < 4; ++ni)
                    acc[mi][ni] = __builtin_amdgcn_mfma_f32_16x16x32_bf16(
                        af[mi], bfq[ni], acc[mi][ni], 0, 0, 0);
        }
        // write next tiles into the (single) buffer after all waves finish reading
        if (tstep < 3) {
            __syncthreads();
            #pragma unroll
            for (int ii = 0; ii < 4; ++ii) {
                *(short8*)(As + sr[ii] * 64 + swz(skc[ii], sr[ii]) * 8) = aregs[ii];
                *(short8*)(Bs + sr[ii] * 64 + swz(skc[ii], sr[ii]) * 8) = bregs[ii];
            }
            __syncthreads();
        }
    }

    // --- epilogue phase 1: C fragments -> LDS (bf16, [r][c] stride 136) ---
    __syncthreads();
    #pragma unroll
    for (int ni = 0; ni < 4; ++ni) {
        int col = wc * 64 + ni * 16 + lm;
        float bv = bias[n0 + col];
        #pragma unroll
        for (int mi = 0; mi < 4; ++mi) {
            int rowb = wr * 64 + mi * 16 + lq * 4;
            #pragma unroll
            for (int rr = 0; rr < 4; ++rr)
                SM[(rowb + rr) * 136 + col] = f2s(acc[mi][ni][rr] + bv);
        }
    }
    __syncthreads();
    // --- epilogue phase 2: coalesced row-contiguous 16B stores ---
    #pragma unroll
    for (int it = 0; it < 8; ++it) {
        int idx = it * 256 + t;
        int r = idx >> 4, c8 = idx & 15;
        int row = m0 + r;
        if (row < N_TOT) {
            int colbase = n0 + (c8 >> 3) * 64;
            int sel = colbase >> 8;                 // 0=Q 1=K 2=V
            int cc = (colbase & 255) + (c8 & 7) * 8;
            short8 v = *(const short8*)(SM + r * 136 + c8 * 8);
            short* dp;
            if (sel == 0) {
                dp = (short*)Qb + (size_t)row * DIMM + cc;
            } else {
                int head = cc >> 5, dim = cc & 31;  // dim in {0,8,16,24}
                int pr = head >> 1, sub = head & 1;
                dp = (short*)KVp + ((size_t)pr * N_TOT + row) * 128
                   + (sel - 1) * 64 + sub * 32 + dim;
            }
            *(short8*)dp = v;
        }
    }
}

// ---------------------------------------------------------------------------
// Output projection (MFMA): O(16384x256 bf16) @ Wout + bout -> out fp32.
// Single-buffered LDS + T14 reg-prefetch (R21).
// ---------------------------------------------------------------------------
__global__ __launch_bounds__(256) void out_mfma(
    const bf16* __restrict__ O, const bf16* __restrict__ Wt,
    const float* __restrict__ bias, float* __restrict__ out)
{
    const int b = blockIdx.x;
    const int xcd = b & 7;
    const int i = b >> 3;                      // 0..31
    const int m0 = (xcd + 8 * (i >> 1)) * 128; // exact cover 0..127
    const int n0 = (i & 1) * 128;

    __shared__ __align__(16) short SM[128 * 136];
    short* As = SM;
    short* Bs = SM + 8192;
    float* CF = (float*)SM;
    const int t  = threadIdx.x;
    const int wid = t >> 6, lane = t & 63;
    const int wr = wid >> 1, wc = wid & 1;
    const int lm = lane & 15, lq = lane >> 4;

    f32x4 acc[4][4] = {};
    short8 aregs[4], bregs[4];

    int sr[4], skc[4];
    #pragma unroll
    for (int ii = 0; ii < 4; ++ii) {
        int c8 = t + 256 * ii;
        sr[ii] = c8 >> 3; skc[ii] = c8 & 7;
    }

    // prologue: stage step 0
    #pragma unroll
    for (int ii = 0; ii < 4; ++ii) {
        aregs[ii] = *(const short8*)((const short*)O + (size_t)(m0 + sr[ii]) * DIMM + skc[ii] * 8);
        bregs[ii] = *(const short8*)((const short*)Wt + (size_t)(n0 + sr[ii]) * 256 + skc[ii] * 8);
    }
    #pragma unroll
    for (int ii = 0; ii < 4; ++ii) {
        *(short8*)(As + sr[ii] * 64 + swz(skc[ii], sr[ii]) * 8) = aregs[ii];
        *(short8*)(Bs + sr[ii] * 64 + swz(skc[ii], sr[ii]) * 8) = bregs[ii];
    }
    __syncthreads();

    #pragma unroll
    for (int tstep = 0; tstep < 4; ++tstep) {
        if (tstep < 3) {
            const int kn = (tstep + 1) * 64;
            #pragma unroll
            for (int ii = 0; ii < 4; ++ii) {
                aregs[ii] = *(const short8*)((const short*)O + (size_t)(m0 + sr[ii]) * DIMM + kn + skc[ii] * 8);
                bregs[ii] = *(const short8*)((const short*)Wt + (size_t)(n0 + sr[ii]) * 256 + kn + skc[ii] * 8);
            }
        }
        #pragma unroll
        for (int kk = 0; kk < 2; ++kk) {
            const int c = kk * 4 + lq;
            short8 af[4], bfq[4];
            #pragma unroll
            for (int mi = 0; mi < 4; ++mi) {
                int r = wr * 64 + mi * 16 + lm;
                af[mi] = *(const short8*)(As + r * 64 + swz(c, r) * 8);
            }
            #pragma unroll
            for (int ni = 0; ni < 4; ++ni) {
                int n = wc * 64 + ni * 16 + lm;
                bfq[ni] = *(const short8*)(Bs + n * 64 + swz(c, n) * 8);
            }
            #pragma unroll
            for (int mi = 0; mi < 4; ++mi)
                #pragma unroll
                for (int ni = 0; ni < 4; ++ni)
                    acc[mi][ni] = __builtin_amdgcn_mfma_f32_16x16x32_bf16(
                        af[mi], bfq[ni], acc[mi][ni], 0, 0, 0);
        }
        if (tstep < 3) {
            __syncthreads();
            #pragma unroll
            for (int ii = 0; ii < 4; ++ii) {
                *(short8*)(As + sr[ii] * 64 + swz(skc[ii], sr[ii]) * 8) = aregs[ii];
                *(short8*)(Bs + sr[ii] * 64 + swz(skc[ii], sr[ii]) * 8) = bregs[ii];
            }
            __syncthreads();
        }
    }

    // --- epilogue: two 64-row fp32 passes through LDS ---
    #pragma unroll
    for (int p = 0; p < 2; ++p) {
        __syncthreads();
        if (wr == p) {
            #pragma unroll
            for (int ni = 0; ni < 4; ++ni) {
                int col = wc * 64 + ni * 16 + lm;
                float bv = bias[n0 + col];
                #pragma unroll
                for (int mi = 0; mi < 4; ++mi) {
                    int lr = mi * 16 + lq * 4;
                    #pragma unroll
                    for (int rr = 0; rr < 4; ++rr) {
                        float val = acc[mi][ni][rr] + bv;
                        val = fminf(fmaxf(val, -1e4f), 1e4f);  // tripwire
                        CF[(lr + rr) * 132 + col] = val;
                    }
                }
            }
        }
        __syncthreads();
        #pragma unroll
        for (int it = 0; it < 8; ++it) {
            int idx = it * 256 + t;
            int r = idx >> 5, c4 = idx & 31;
            float4 v = *(const float4*)(CF + r * 132 + c4 * 4);
            *(float4*)(out + (size_t)(m0 + p * 64 + r) * DIMM + n0 + c4 * 4) = v;
        }
    }
}

// ---------------------------------------------------------------------------
// Gather attention (R22): HEAD-PAIR split with XCD affinity (R19 structure).
// One wave per (node, head-pair); pair = blockIdx & 3; per-XCD KV slab
// 4.2 MB ~ L2. 8 edge-groups x 8 lanes; one ushort8 K-load covers BOTH
// heads, ditto V. NEW: K-score via packed v_dot2_f32_bf16 on the raw
// loaded registers (4 dot2 replace 8 cvt + 8 FMA per lane per edge; scale
// applied once after the dot). Scalar fallback if builtin missing.
// Score reduce shfl_xor 1,2; epilogue reduce xor 8,16,32. Adjacency
// register-resident; ping-pong. ii = base+g-5: -5=self, -4..-1=globals.
// ---------------------------------------------------------------------------
__global__ __launch_bounds__(256) void attn_kernel(
    const bf16* __restrict__ Qb, const bf16* __restrict__ KVp,
    const int* __restrict__ cnt, const unsigned short* __restrict__ adjP,
    bf16* __restrict__ Ob)
{
    const int b = blockIdx.x;
    const int pair = b & 3;                    // heads {2p, 2p+1}
    const int wid = threadIdx.x >> 6;
    const int lane = threadIdx.x & 63;
    const int n = (b >> 2) * 4 + wid;          // 0..16383
    const int g = lane >> 3, j = lane & 7;     // edge-group; 16B chunk within pair-row
    const float scale = 0.1767766952966369f;   // 32^-0.5

    // pair slab: [node][Ka 64B|Kb 64B|Va 64B|Vb 64B] = 128 shorts/node
    const unsigned short* KV = (const unsigned short*)KVp + (size_t)pair * N_TOT * 128;

    // lane's head = pair*2 + (j>>2); lane's dims = 8*(j&3) .. +7
    const int hoff = (pair * 2 + (j >> 2)) * 32 + (j & 3) * 8;
    ush8 qu = *(const ush8*)((const unsigned short*)Qb + (size_t)n * DIMM + hoff);
#if HAVE_FDOT2
    const uint4 qw = __builtin_bit_cast(uint4, qu);   // 4 packed bf16 pairs
#else
    float qf[8];
    #pragma unroll
    for (int e = 0; e < 8; ++e) qf[e] = bu2f(qu[e]);
#endif

    const int areg = adjP[(n << 6) + lane];    // whole adj row in regs
    const int deg = min(cnt[n], ADJ_CAP);
    const int tot = deg + 5;

    float acc[8] = {0.f, 0.f, 0.f, 0.f, 0.f, 0.f, 0.f, 0.f};
    float dsum = 0.f;

    auto IDX = [&](int base, int& sv, float& ok) {
        int ii = base + g - 5;
        bool val = (ii < deg);
        int sg = __shfl(areg, ii & 63);        // group-uniform broadcast
        int s  = (ii < 0) ? ((ii == -5) ? n : (N_NODES + ii + 4)) : sg;
        sv = val ? s : n;                      // invalid -> self row (hot)
        ok = val ? 1.f : 0.f;
    };

    auto SCORE = [&](const ush8& kk) -> float {
#if HAVE_FDOT2
        uint4 kw = __builtin_bit_cast(uint4, kk);
        float p = __builtin_amdgcn_fdot2_f32_bf16(
            __builtin_bit_cast(bf16x2, qw.x), __builtin_bit_cast(bf16x2, kw.x), 0.f, false);
        p = __builtin_amdgcn_fdot2_f32_bf16(
            __builtin_bit_cast(bf16x2, qw.y), __builtin_bit_cast(bf16x2, kw.y), p, false);
        p = __builtin_amdgcn_fdot2_f32_bf16(
            __builtin_bit_cast(bf16x2, qw.z), __builtin_bit_cast(bf16x2, kw.z), p, false);
        p = __builtin_amdgcn_fdot2_f32_bf16(
            __builtin_bit_cast(bf16x2, qw.w), __builtin_bit_cast(bf16x2, kw.w), p, false);
        return p;
#else
        return qf[0] * bu2f(kk[0]) + qf[1] * bu2f(kk[1])
             + qf[2] * bu2f(kk[2]) + qf[3] * bu2f(kk[3])
             + qf[4] * bu2f(kk[4]) + qf[5] * bu2f(kk[5])
             + qf[6] * bu2f(kk[6]) + qf[7] * bu2f(kk[7]);
#endif
    };

    int svA; float okA;
    IDX(0, svA, okA);
    ush8 kA = *(const ush8*)(KV + (size_t)svA * 128 + j * 8);
    ush8 vA = *(const ush8*)(KV + (size_t)svA * 128 + 64 + j * 8);

    int base = 0;
    while (true) {
        int svB; float okB; ush8 kB, vB;
        const bool more = (base + 8 < tot);
        if (more) {
            IDX(base + 8, svB, okB);
            kB = *(const ush8*)(KV + (size_t)svB * 128 + j * 8);
            vB = *(const ush8*)(KV + (size_t)svB * 128 + 64 + j * 8);
        }
        // process current: per-head score via 4-lane reduce
        {
            float p = SCORE(kA);
            p += __shfl_xor(p, 1);
            p += __shfl_xor(p, 2);
            float wgt = okA * __expf(fminf(p * scale, 80.f));
            dsum += wgt;
            #pragma unroll
            for (int e = 0; e < 8; ++e) acc[e] += wgt * bu2f(vA[e]);
        }
        if (!more) break;
        base += 8;
        svA = svB; okA = okB; kA = kB; vA = vB;
    }

    // cross-group reduction (8 groups hold disjoint edge subsets per head)
    #pragma unroll
    for (int m = 8; m <= 32; m <<= 1) {
        #pragma unroll
        for (int e = 0; e < 8; ++e) acc[e] += __shfl_xor(acc[e], m);
        dsum += __shfl_xor(dsum, m);
    }

    if (g == 0) {                               // lanes 0..7 write both heads
        float r = 1.0f / fmaxf(dsum, 1e-30f);   // tripwire
        ush8 o;
        #pragma unroll
        for (int e = 0; e < 8; ++e) {
            float v = fminf(fmaxf(acc[e] * r, -500.f), 500.f);
            o[e] = (unsigned short)__builtin_bit_cast(short, __float2bfloat16(v));
        }
        *(ush8*)((unsigned short*)Ob + (size_t)n * DIMM + hoff) = o;
    }
}

// ---------------------------------------------------------------------------
extern "C" void kernel_launch(void* const* d_in, const int* in_sizes, int n_in,
                              void* d_out, int out_size, void* d_ws, size_t ws_size,
                              hipStream_t stream)
{
    const float* x    = (const float*)d_in[0];
    const int*   ei   = (const int*)d_in[1];
    const int*   xei  = (const int*)d_in[2];
    const float* Wqkv = (const float*)d_in[3];
    const float* bqkv = (const float*)d_in[4];
    const float* Wout = (const float*)d_in[5];
    const float* bout = (const float*)d_in[6];
    const float* gtok = (const float*)d_in[7];

    // workspace layout (~37 MB):
    int* cnt  = (int*)d_ws;                           // N_NODES (zeroed in prep)
    unsigned short* adjP = (unsigned short*)(cnt + N_NODES);  // N_NODES*64 u16 (2 MB)
    uintptr_t fb = ((uintptr_t)(adjP + (size_t)N_NODES * ADJ_CAP) + 15) & ~(uintptr_t)15;
    bf16*  Qb  = (bf16*)fb;                           // bf16, N_TOT*256
    bf16*  KVp = Qb + (size_t)N_TOT * DIMM;           // bf16, 4 pairs x N_TOT x 128 (pair-split K|V)
    bf16*  Ob  = KVp + (size_t)N_TOT * 512;           // bf16, N_NODES*256
    bf16*  Wt1 = Ob + (size_t)N_NODES * DIMM;         // bf16, 768*256
    bf16*  Wt2 = Wt1 + 768 * 256;                     // bf16, 256*256

    // 4 dispatches, no memset (cnt zeroed in prep; edge-build fused into qkv)
    prep_kernel<<<80, 256, 0, stream>>>(Wqkv, Wout, Wt1, Wt2, cnt);
    qkv_mfma<<<768 + 816, 256, 0, stream>>>(x, gtok, Wt1, bqkv, ei, xei, cnt, adjP, Qb, KVp);
    attn_kernel<<<(N_NODES / 4) * 4, 256, 0, stream>>>(Qb, KVp, cnt, adjP, Ob);
    out_mfma<<<256, 256, 0, stream>>>(Ob, Wt2, bout, (float*)d_out);
}

// Round 11
// 144.016 us; speedup vs baseline: 1.0280x; 1.0280x over previous
//
#include <hip/hip_runtime.h>
#include <hip/hip_bf16.h>
#include <stdint.h>

#define N_NODES   16384
#define DIMM      256
#define HEADS     8
#define HDIM      32
#define NUM_GLOBAL 4
#define N_TOT     (N_NODES + NUM_GLOBAL)   // 16388
#define E_LOCAL   131072
#define E_EXP     65536
#define E_CSR     (E_LOCAL + E_EXP)        // 196608
#define ADJ_CAP   64                       // P(Poisson(12) >= 64) ~ 1e-26

typedef __hip_bfloat16 bf16;
typedef __attribute__((ext_vector_type(8))) short short8;
typedef __attribute__((ext_vector_type(8))) unsigned short ush8;
typedef __attribute__((ext_vector_type(4))) short sh4;
typedef __attribute__((ext_vector_type(4))) float f32x4;

__device__ __forceinline__ short f2s(float f) {
    bf16 h = __float2bfloat16(f);
    return __builtin_bit_cast(short, h);
}
__device__ __forceinline__ float bu2f(unsigned short u) {
    return __bfloat162float(__builtin_bit_cast(bf16, u));
}

// XOR swizzle: 16B chunk c of row r stored at chunk (c ^ (r&7) ^ ((r>>3)&7)).
__device__ __forceinline__ int swz(int c, int r) {
    return c ^ (r & 7) ^ ((r >> 3) & 7);
}

// ---------------------------------------------------------------------------
// prep (R20): (a) transpose Wqkv -> Wt1 bf16; (b) transpose Wout -> Wt2 bf16
//       (c) convert X||gtok fp32 -> Xb bf16
//       (d) ZERO cnt (16 of the convert blocks; replaces hipMemsetAsync)
// Grid: 64 transpose + 2049 convert = 2113 blocks.
// ---------------------------------------------------------------------------
__global__ __launch_bounds__(256) void prep_kernel(
    const float* __restrict__ Wqkv, const float* __restrict__ Wout,
    const float* __restrict__ x, const float* __restrict__ gtok,
    bf16* __restrict__ Wt1, bf16* __restrict__ Wt2,
    int* __restrict__ cnt, bf16* __restrict__ Xb)
{
    const int b = blockIdx.x;
    const int t = threadIdx.x;
    if (b < 64) {
        __shared__ float T[64][65];
        const float* src; bf16* dst; int n0, k0, ldn;
        if (b < 48) { src = Wqkv; dst = Wt1; n0 = (b % 12) * 64; k0 = (b / 12) * 64; ldn = 768; }
        else        { int bb = b - 48; src = Wout; dst = Wt2; n0 = (bb & 3) * 64; k0 = (bb >> 2) * 64; ldn = 256; }
        #pragma unroll
        for (int i = 0; i < 4; ++i) {
            int idx = t + 256 * i;
            int r = idx >> 4, c4 = (idx & 15) * 4;
            float4 v = *(const float4*)(src + (size_t)(k0 + r) * ldn + n0 + c4);
            T[r][c4] = v.x; T[r][c4 + 1] = v.y; T[r][c4 + 2] = v.z; T[r][c4 + 3] = v.w;
        }
        __syncthreads();
        #pragma unroll
        for (int i = 0; i < 4; ++i) {
            int idx = t + 256 * i;
            int nr = idx >> 4, kk = (idx & 15) * 4;
            sh4 o;
            o[0] = f2s(T[kk][nr]);     o[1] = f2s(T[kk + 1][nr]);
            o[2] = f2s(T[kk + 2][nr]); o[3] = f2s(T[kk + 3][nr]);
            *(sh4*)(dst + (size_t)(n0 + nr) * 256 + k0 + kk) = o;
        }
    } else {
        // first 16 convert blocks also zero cnt (16*256 int4 = 16384 ints)
        if (b < 80) {
            ((int4*)cnt)[(b - 64) * 256 + t] = make_int4(0, 0, 0, 0);
        }
        // convert 8 consecutive elements per thread
        int e0 = ((b - 64) * 256 + t) * 8;
        if (e0 < N_TOT * DIMM) {
            int row = e0 >> 8, col = e0 & 255;
            const float* p = (row < N_NODES)
                ? x + (size_t)row * DIMM + col
                : gtok + (size_t)(row - N_NODES) * DIMM + col;
            float4 v0 = *(const float4*)p, v1 = *(const float4*)(p + 4);
            short8 o;
            o[0] = f2s(v0.x); o[1] = f2s(v0.y); o[2] = f2s(v0.z); o[3] = f2s(v0.w);
            o[4] = f2s(v1.x); o[5] = f2s(v1.y); o[6] = f2s(v1.z); o[7] = f2s(v1.w);
            *(short8*)((short*)Xb + (size_t)row * DIMM + col) = o;
        }
    }
}

// ---------------------------------------------------------------------------
// QKV projection + fused edge-build. Blocks 0..767: padded-adjacency build.
// Blocks 768+: Xb(16388x256 bf16) @ Wqkv + b -> Qb + pair-split KVp.
// R21: SINGLE-buffered LDS (34.8 KB union, staging in first 32 KB) with T14
// reg-prefetch: next step's A+B tiles load into regs BEFORE compute, written
// to LDS between two barriers after compute. Same barrier count as the old
// 64 KB dbuf, half the LDS -> LDS-allowed occupancy 2 -> 4 blocks/CU.
// ---------------------------------------------------------------------------
__global__ __launch_bounds__(256) void qkv_mfma(
    const bf16* __restrict__ Xb, const bf16* __restrict__ Wt,
    const float* __restrict__ bias,
    const int* __restrict__ ei, const int* __restrict__ xei,
    int* __restrict__ cnt, unsigned short* __restrict__ adjP,
    bf16* __restrict__ Qb, bf16* __restrict__ KVp)
{
    const int braw = blockIdx.x;
    const int t  = threadIdx.x;
    if (braw < 768) {
        int e = braw * 256 + t;
        int s, d;
        if (e < E_LOCAL) { s = ei[e];            d = ei[E_LOCAL + e]; }
        else             { int ee = e - E_LOCAL; s = xei[ee]; d = xei[E_EXP + ee]; }
        int pos = atomicAdd(&cnt[d], 1);
        if (pos < ADJ_CAP) adjP[(d << 6) + pos] = (unsigned short)s;
        return;
    }
    const int b = braw - 768;
    const int xcd = b & 7;
    const int i = b >> 3;                      // 0..101
    const int mt = xcd + 8 * (i / 6);          // m-tile 0..135
    if (mt >= 129) return;
    const int m0 = mt * 128;
    const int n0 = (i % 6) * 128;              // 0..640

    __shared__ __align__(16) short SM[128 * 136];  // 34.8 KB union
    short* As = SM;                  // [128][64] staging (8192 shorts)
    short* Bs = SM + 8192;           // [128][64] staging
    const int wid = t >> 6, lane = t & 63;
    const int wr = wid >> 1, wc = wid & 1;
    const int lm = lane & 15, lq = lane >> 4;

    f32x4 acc[4][4] = {};
    short8 aregs[4], bregs[4];

    int sr[4], skc[4];
    #pragma unroll
    for (int ii = 0; ii < 4; ++ii) {
        int c8 = t + 256 * ii;
        sr[ii] = c8 >> 3; skc[ii] = c8 & 7;
    }

    // prologue: stage step 0
    #pragma unroll
    for (int ii = 0; ii < 4; ++ii) {
        aregs[ii] = *(const short8*)((const short*)Xb + (size_t)(m0 + sr[ii]) * DIMM + skc[ii] * 8);
        bregs[ii] = *(const short8*)((const short*)Wt + (size_t)(n0 + sr[ii]) * 256 + skc[ii] * 8);
    }
    #pragma unroll
    for (int ii = 0; ii < 4; ++ii) {
        *(short8*)(As + sr[ii] * 64 + swz(skc[ii], sr[ii]) * 8) = aregs[ii];
        *(short8*)(Bs + sr[ii] * 64 + swz(skc[ii], sr[ii]) * 8) = bregs[ii];
    }
    __syncthreads();

    #pragma unroll
    for (int tstep = 0; tstep < 4; ++tstep) {
        // T14: issue next step's loads before compute
        if (tstep < 3) {
            const int kn = (tstep + 1) * 64;
            #pragma unroll
            for (int ii = 0; ii < 4; ++ii) {
                aregs[ii] = *(const short8*)((const short*)Xb + (size_t)(m0 + sr[ii]) * DIMM + kn + skc[ii] * 8);
                bregs[ii] = *(const short8*)((const short*)Wt + (size_t)(n0 + sr[ii]) * 256 + kn + skc[ii] * 8);
            }
        }
        // compute on current buffer
        #pragma unroll
        for (int kk = 0; kk < 2; ++kk) {
            const int c = kk * 4 + lq;
            short8 af[4], bfq[4];
            #pragma unroll
            for (int mi = 0; mi < 4; ++mi) {
                int r = wr * 64 + mi * 16 + lm;
                af[mi] = *(const short8*)(As + r * 64 + swz(c, r) * 8);
            }
            #pragma unroll
            for (int ni = 0; ni < 4; ++ni) {
                int n = wc * 64 + ni * 16 + lm;
                bfq[ni] = *(const short8*)(Bs + n * 64 + swz(c, n) * 8);
            }
            #pragma unroll
            for (int mi = 0; mi < 4; ++mi)
                #pragma unroll
                for (int ni = 0; ni < 4; ++ni)
                    acc[mi][ni] = __builtin_amdgcn_mfma_f32_16x16x32_bf16(
                        af[mi], bfq[ni], acc[mi][ni], 0, 0, 0);
        }
        // write next tiles into the (single) buffer after all waves finish reading
        if (tstep < 3) {
            __syncthreads();
            #pragma unroll
            for (int ii = 0; ii < 4; ++ii) {
                *(short8*)(As + sr[ii] * 64 + swz(skc[ii], sr[ii]) * 8) = aregs[ii];
                *(short8*)(Bs + sr[ii] * 64 + swz(skc[ii], sr[ii]) * 8) = bregs[ii];
            }
            __syncthreads();
        }
    }

    // --- epilogue phase 1: C fragments -> LDS (bf16, [r][c] stride 136) ---
    __syncthreads();
    #pragma unroll
    for (int ni = 0; ni < 4; ++ni) {
        int col = wc * 64 + ni * 16 + lm;
        float bv = bias[n0 + col];
        #pragma unroll
        for (int mi = 0; mi < 4; ++mi) {
            int rowb = wr * 64 + mi * 16 + lq * 4;
            #pragma unroll
            for (int rr = 0; rr < 4; ++rr)
                SM[(rowb + rr) * 136 + col] = f2s(acc[mi][ni][rr] + bv);
        }
    }
    __syncthreads();
    // --- epilogue phase 2: coalesced row-contiguous 16B stores ---
    #pragma unroll
    for (int it = 0; it < 8; ++it) {
        int idx = it * 256 + t;
        int r = idx >> 4, c8 = idx & 15;
        int row = m0 + r;
        if (row < N_TOT) {
            int colbase = n0 + (c8 >> 3) * 64;
            int sel = colbase >> 8;                 // 0=Q 1=K 2=V
            int cc = (colbase & 255) + (c8 & 7) * 8;
            short8 v = *(const short8*)(SM + r * 136 + c8 * 8);
            short* dp;
            if (sel == 0) {
                dp = (short*)Qb + (size_t)row * DIMM + cc;
            } else {
                int head = cc >> 5, dim = cc & 31;  // dim in {0,8,16,24}
                int pr = head >> 1, sub = head & 1;
                dp = (short*)KVp + ((size_t)pr * N_TOT + row) * 128
                   + (sel - 1) * 64 + sub * 32 + dim;
            }
            *(short8*)dp = v;
        }
    }
}

// ---------------------------------------------------------------------------
// Output projection (MFMA): O(16384x256 bf16) @ Wout + bout -> out fp32.
// R21: added T14 reg-prefetch (next K-step's tiles load into regs before
// compute) -- the old loop exposed full global-load latency every step.
// ---------------------------------------------------------------------------
__global__ __launch_bounds__(256) void out_mfma(
    const bf16* __restrict__ O, const bf16* __restrict__ Wt,
    const float* __restrict__ bias, float* __restrict__ out)
{
    const int b = blockIdx.x;
    const int xcd = b & 7;
    const int i = b >> 3;                      // 0..31
    const int m0 = (xcd + 8 * (i >> 1)) * 128; // exact cover 0..127
    const int n0 = (i & 1) * 128;

    __shared__ __align__(16) short SM[128 * 136];
    short* As = SM;
    short* Bs = SM + 8192;
    float* CF = (float*)SM;
    const int t  = threadIdx.x;
    const int wid = t >> 6, lane = t & 63;
    const int wr = wid >> 1, wc = wid & 1;
    const int lm = lane & 15, lq = lane >> 4;

    f32x4 acc[4][4] = {};
    short8 aregs[4], bregs[4];

    int sr[4], skc[4];
    #pragma unroll
    for (int ii = 0; ii < 4; ++ii) {
        int c8 = t + 256 * ii;
        sr[ii] = c8 >> 3; skc[ii] = c8 & 7;
    }

    // prologue: stage step 0
    #pragma unroll
    for (int ii = 0; ii < 4; ++ii) {
        aregs[ii] = *(const short8*)((const short*)O + (size_t)(m0 + sr[ii]) * DIMM + skc[ii] * 8);
        bregs[ii] = *(const short8*)((const short*)Wt + (size_t)(n0 + sr[ii]) * 256 + skc[ii] * 8);
    }
    #pragma unroll
    for (int ii = 0; ii < 4; ++ii) {
        *(short8*)(As + sr[ii] * 64 + swz(skc[ii], sr[ii]) * 8) = aregs[ii];
        *(short8*)(Bs + sr[ii] * 64 + swz(skc[ii], sr[ii]) * 8) = bregs[ii];
    }
    __syncthreads();

    #pragma unroll
    for (int tstep = 0; tstep < 4; ++tstep) {
        if (tstep < 3) {
            const int kn = (tstep + 1) * 64;
            #pragma unroll
            for (int ii = 0; ii < 4; ++ii) {
                aregs[ii] = *(const short8*)((const short*)O + (size_t)(m0 + sr[ii]) * DIMM + kn + skc[ii] * 8);
                bregs[ii] = *(const short8*)((const short*)Wt + (size_t)(n0 + sr[ii]) * 256 + kn + skc[ii] * 8);
            }
        }
        #pragma unroll
        for (int kk = 0; kk < 2; ++kk) {
            const int c = kk * 4 + lq;
            short8 af[4], bfq[4];
            #pragma unroll
            for (int mi = 0; mi < 4; ++mi) {
                int r = wr * 64 + mi * 16 + lm;
                af[mi] = *(const short8*)(As + r * 64 + swz(c, r) * 8);
            }
            #pragma unroll
            for (int ni = 0; ni < 4; ++ni) {
                int n = wc * 64 + ni * 16 + lm;
                bfq[ni] = *(const short8*)(Bs + n * 64 + swz(c, n) * 8);
            }
            #pragma unroll
            for (int mi = 0; mi < 4; ++mi)
                #pragma unroll
                for (int ni = 0; ni < 4; ++ni)
                    acc[mi][ni] = __builtin_amdgcn_mfma_f32_16x16x32_bf16(
                        af[mi], bfq[ni], acc[mi][ni], 0, 0, 0);
        }
        if (tstep < 3) {
            __syncthreads();
            #pragma unroll
            for (int ii = 0; ii < 4; ++ii) {
                *(short8*)(As + sr[ii] * 64 + swz(skc[ii], sr[ii]) * 8) = aregs[ii];
                *(short8*)(Bs + sr[ii] * 64 + swz(skc[ii], sr[ii]) * 8) = bregs[ii];
            }
            __syncthreads();
        }
    }

    // --- epilogue: two 64-row fp32 passes through LDS ---
    #pragma unroll
    for (int p = 0; p < 2; ++p) {
        __syncthreads();
        if (wr == p) {
            #pragma unroll
            for (int ni = 0; ni < 4; ++ni) {
                int col = wc * 64 + ni * 16 + lm;
                float bv = bias[n0 + col];
                #pragma unroll
                for (int mi = 0; mi < 4; ++mi) {
                    int lr = mi * 16 + lq * 4;
                    #pragma unroll
                    for (int rr = 0; rr < 4; ++rr) {
                        float val = acc[mi][ni][rr] + bv;
                        val = fminf(fmaxf(val, -1e4f), 1e4f);  // tripwire
                        CF[(lr + rr) * 132 + col] = val;
                    }
                }
            }
        }
        __syncthreads();
        #pragma unroll
        for (int it = 0; it < 8; ++it) {
            int idx = it * 256 + t;
            int r = idx >> 5, c4 = idx & 31;
            float4 v = *(const float4*)(CF + r * 132 + c4 * 4);
            *(float4*)(out + (size_t)(m0 + p * 64 + r) * DIMM + n0 + c4 * 4) = v;
        }
    }
}

// ---------------------------------------------------------------------------
// Gather attention, R19 (unchanged): HEAD-PAIR split with XCD affinity.
// One wave per (node, head-pair); pair = blockIdx & 3; per-XCD KV slab
// 4.2 MB ~ L2. 8 edge-groups x 8 lanes; one ushort8 K-load covers BOTH
// heads, ditto V. Score reduce shfl_xor 1,2; epilogue reduce xor 8,16,32.
// Adjacency register-resident; ping-pong. ii = base+g-5.
// ---------------------------------------------------------------------------
__global__ __launch_bounds__(256) void attn_kernel(
    const bf16* __restrict__ Qb, const bf16* __restrict__ KVp,
    const int* __restrict__ cnt, const unsigned short* __restrict__ adjP,
    bf16* __restrict__ Ob)
{
    const int b = blockIdx.x;
    const int pair = b & 3;                    // heads {2p, 2p+1}
    const int wid = threadIdx.x >> 6;
    const int lane = threadIdx.x & 63;
    const int n = (b >> 2) * 4 + wid;          // 0..16383
    const int g = lane >> 3, j = lane & 7;     // edge-group; 16B chunk within pair-row
    const float scale = 0.1767766952966369f;   // 32^-0.5

    // pair slab: [node][Ka 64B|Kb 64B|Va 64B|Vb 64B] = 128 shorts/node
    const unsigned short* KV = (const unsigned short*)KVp + (size_t)pair * N_TOT * 128;

    // lane's head = pair*2 + (j>>2); lane's dims = 8*(j&3) .. +7
    const int hoff = (pair * 2 + (j >> 2)) * 32 + (j & 3) * 8;
    ush8 qu = *(const ush8*)((const unsigned short*)Qb + (size_t)n * DIMM + hoff);
    float qf[8];
    #pragma unroll
    for (int e = 0; e < 8; ++e) qf[e] = bu2f(qu[e]) * scale;

    const int areg = adjP[(n << 6) + lane];    // whole adj row in regs
    const int deg = min(cnt[n], ADJ_CAP);
    const int tot = deg + 5;

    float acc[8] = {0.f, 0.f, 0.f, 0.f, 0.f, 0.f, 0.f, 0.f};
    float dsum = 0.f;

    auto IDX = [&](int base, int& sv, float& ok) {
        int ii = base + g - 5;
        bool val = (ii < deg);
        int sg = __shfl(areg, ii & 63);        // group-uniform broadcast
        int s  = (ii < 0) ? ((ii == -5) ? n : (N_NODES + ii + 4)) : sg;
        sv = val ? s : n;                      // invalid -> self row (hot)
        ok = val ? 1.f : 0.f;
    };

    int svA; float okA;
    IDX(0, svA, okA);
    ush8 kA = *(const ush8*)(KV + (size_t)svA * 128 + j * 8);
    ush8 vA = *(const ush8*)(KV + (size_t)svA * 128 + 64 + j * 8);

    int base = 0;
    while (true) {
        int svB; float okB; ush8 kB, vB;
        const bool more = (base + 8 < tot);
        if (more) {
            IDX(base + 8, svB, okB);
            kB = *(const ush8*)(KV + (size_t)svB * 128 + j * 8);
            vB = *(const ush8*)(KV + (size_t)svB * 128 + 64 + j * 8);
        }
        // process current: per-head score via 4-lane reduce
        {
            float p = qf[0] * bu2f(kA[0]) + qf[1] * bu2f(kA[1])
                    + qf[2] * bu2f(kA[2]) + qf[3] * bu2f(kA[3])
                    + qf[4] * bu2f(kA[4]) + qf[5] * bu2f(kA[5])
                    + qf[6] * bu2f(kA[6]) + qf[7] * bu2f(kA[7]);
            p += __shfl_xor(p, 1);
            p += __shfl_xor(p, 2);
            float wgt = okA * __expf(fminf(p, 80.f));
            dsum += wgt;
            #pragma unroll
            for (int e = 0; e < 8; ++e) acc[e] += wgt * bu2f(vA[e]);
        }
        if (!more) break;
        base += 8;
        svA = svB; okA = okB; kA = kB; vA = vB;
    }

    // cross-group reduction (8 groups hold disjoint edge subsets per head)
    #pragma unroll
    for (int m = 8; m <= 32; m <<= 1) {
        #pragma unroll
        for (int e = 0; e < 8; ++e) acc[e] += __shfl_xor(acc[e], m);
        dsum += __shfl_xor(dsum, m);
    }

    if (g == 0) {                               // lanes 0..7 write both heads
        float r = 1.0f / fmaxf(dsum, 1e-30f);   // tripwire
        ush8 o;
        #pragma unroll
        for (int e = 0; e < 8; ++e) {
            float v = fminf(fmaxf(acc[e] * r, -500.f), 500.f);
            o[e] = (unsigned short)__builtin_bit_cast(short, __float2bfloat16(v));
        }
        *(ush8*)((unsigned short*)Ob + (size_t)n * DIMM + hoff) = o;
    }
}

// ---------------------------------------------------------------------------
extern "C" void kernel_launch(void* const* d_in, const int* in_sizes, int n_in,
                              void* d_out, int out_size, void* d_ws, size_t ws_size,
                              hipStream_t stream)
{
    const float* x    = (const float*)d_in[0];
    const int*   ei   = (const int*)d_in[1];
    const int*   xei  = (const int*)d_in[2];
    const float* Wqkv = (const float*)d_in[3];
    const float* bqkv = (const float*)d_in[4];
    const float* Wout = (const float*)d_in[5];
    const float* bout = (const float*)d_in[6];
    const float* gtok = (const float*)d_in[7];

    // workspace layout (~45 MB):
    int* cnt  = (int*)d_ws;                           // N_NODES (zeroed in prep)
    unsigned short* adjP = (unsigned short*)(cnt + N_NODES);  // N_NODES*64 u16 (2 MB)
    uintptr_t fb = ((uintptr_t)(adjP + (size_t)N_NODES * ADJ_CAP) + 15) & ~(uintptr_t)15;
    bf16*  Qb  = (bf16*)fb;                           // bf16, N_TOT*256
    bf16*  KVp = Qb + (size_t)N_TOT * DIMM;           // bf16, 4 pairs x N_TOT x 128 (pair-split K|V)
    bf16*  Ob  = KVp + (size_t)N_TOT * 512;           // bf16, N_NODES*256
    bf16*  Wt1 = Ob + (size_t)N_NODES * DIMM;         // bf16, 768*256
    bf16*  Wt2 = Wt1 + 768 * 256;                     // bf16, 256*256
    bf16*  Xb  = Wt2 + 256 * 256;                     // bf16, 16512*256 (129 tiles padded)

    // 4 dispatches, no memset (cnt zeroed in prep; edge-build fused into qkv)
    prep_kernel<<<2113, 256, 0, stream>>>(Wqkv, Wout, x, gtok, Wt1, Wt2, cnt, Xb);
    qkv_mfma<<<768 + 816, 256, 0, stream>>>(Xb, Wt1, bqkv, ei, xei, cnt, adjP, Qb, KVp);
    attn_kernel<<<(N_NODES / 4) * 4, 256, 0, stream>>>(Qb, KVp, cnt, adjP, Ob);
    out_mfma<<<256, 256, 0, stream>>>(Ob, Wt2, bout, (float*)d_out);
}